// Round 9
// baseline (218.546 us; speedup 1.0000x reference)
//
#include <hip/hip_runtime.h>

#define N_NODES 100000
#define E_EDGES 1600000
#define IN_DIM  256
#define OUT_DIM 64
#define SLOPE   0.1f

#define BKT_SHIFT  7
#define BKT_NODES  128
#define NBKT       ((N_NODES + BKT_NODES - 1) / BKT_NODES)   // 782
#define BUCKET_CAP 2560      // mean 2046, sd 45 -> +11 sigma
#define SC_BLOCK   1024
#define SC_EPT     16
#define SC_EDGES   (SC_BLOCK * SC_EPT)                        // 16384
#define SC_GRID    ((E_EDGES + SC_EDGES - 1) / SC_EDGES)      // 98
#define HIST_GRID  1024
#define EMB_BLOCKS ((N_NODES + 63) / 64)                      // 1563

typedef __attribute__((ext_vector_type(8))) short bhalf8;
typedef __attribute__((ext_vector_type(4))) float f32x4;
typedef __attribute__((ext_vector_type(4))) unsigned u32x4;

__device__ __forceinline__ unsigned short f2bf(float x) {
  unsigned u = __float_as_uint(x);
  u = (u + 0x7fffu + ((u >> 16) & 1u)) >> 16;   // RNE
  return (unsigned short)u;
}
__device__ __forceinline__ float bf2f(unsigned short u) {
  return __uint_as_float((unsigned)u << 16);
}
__device__ __forceinline__ unsigned cvtpk(float lo, float hi) {   // RNE pack, 1 inst
  unsigned r;
  asm("v_cvt_pk_bf16_f32 %0, %1, %2" : "=v"(r) : "v"(lo), "v"(hi));
  return r;
}

// -------- K0: zero bucket counters + detect edge layout + W -> bf16 --------
__global__ __launch_bounds__(256) void zero_detect_kernel(
    int* __restrict__ bcnt, const int* __restrict__ edges, int* __restrict__ flag,
    const float* __restrict__ W, short* __restrict__ W16) {
  const int i = blockIdx.x * blockDim.x + threadIdx.x;   // 8 blocks x 256 = 2048
  if (i < NBKT) bcnt[i] = 0;
  if (i == 0) {
    int all0 = 1;
    for (int j = 0; j < 64; ++j)
      if (edges[2 * j + 1] != 0) all0 = 0;
    *flag = all0;  // 1 => int64 layout (high dwords zero), 0 => int32
  }
  {
    const int base = i * 8;
    const float4 f0 = *(const float4*)&W[base];
    const float4 f1 = *(const float4*)&W[base + 4];
    bhalf8 v;
    v[0] = f2bf(f0.x); v[1] = f2bf(f0.y); v[2] = f2bf(f0.z); v[3] = f2bf(f0.w);
    v[4] = f2bf(f1.x); v[5] = f2bf(f1.y); v[6] = f2bf(f1.z); v[7] = f2bf(f1.w);
    *(bhalf8*)&W16[base] = v;
  }
}

// ---------------- K1: emb16 = bf16(X@W^T + b); full-row A upfront; W16 in LDS ----------
template<int KS>
__device__ __forceinline__ void gemm_step(const float4 (&ra)[8][2],
                                          const short* __restrict__ Wlds,
                                          int lg, int lr, int ksw, f32x4 (&acc)[4]) {
  union { u32x4 u; bhalf8 h; } cv;
  cv.u[0] = cvtpk(ra[KS][0].x, ra[KS][0].y);
  cv.u[1] = cvtpk(ra[KS][0].z, ra[KS][0].w);
  cv.u[2] = cvtpk(ra[KS][1].x, ra[KS][1].y);
  cv.u[3] = cvtpk(ra[KS][1].z, ra[KS][1].w);
  bhalf8 bf[4];
  #pragma unroll
  for (int ct = 0; ct < 4; ++ct) {
    const int col_l = ct * 16 + lr;
    bf[ct] = *(const bhalf8*)((const char*)Wlds + col_l * 512 + ((lg * 16 + KS * 64) ^ ksw));
  }
  #pragma unroll
  for (int ct = 0; ct < 4; ++ct)
    acc[ct] = __builtin_amdgcn_mfma_f32_16x16x32_bf16(cv.h, bf[ct], acc[ct], 0, 0, 0);
}

__global__ __launch_bounds__(256) void embed_kernel(
    const float* __restrict__ features, const short* __restrict__ W16,
    const float* __restrict__ bias, const float* __restrict__ a,
    unsigned short* __restrict__ emb16, float* __restrict__ s1, float* __restrict__ s2)
{
  __shared__ short Wlds[64 * 256];    // 32 KB, col stride 512 B, byte^((col&7)<<4)

  const int t = threadIdx.x;
  const int w = t >> 6;
  const int l = t & 63;
  const int lg = l >> 4;      // 0..3  (k-chunk group)
  const int lr = l & 15;      // 0..15 (row/col within tile)
  const int row0 = blockIdx.x * 64 + w * 16;   // this wave's 16 rows

  const int rowc = min(row0 + lr, N_NODES - 1);
  const float* arow = &features[(size_t)rowc * IN_DIM + lg * 8];

  // ---- issue ALL A loads up front (16 dwordx4 per lane, 256 B in flight) ----
  float4 ra[8][2];
  #pragma unroll
  for (int ks = 0; ks < 8; ++ks) {
    ra[ks][0] = *(const float4*)(arow + ks * 32);
    ra[ks][1] = *(const float4*)(arow + ks * 32 + 4);
  }

  // ---- stage W16 -> LDS (pure bf16 copy, swizzled), overlaps A latency ----
  {
    const int col = t >> 2;
    const int kq  = (t & 3) * 64;            // start k (elements)
    const short* src = W16 + col * IN_DIM + kq;
    char* dstbase = (char*)Wlds + col * 512;
    #pragma unroll
    for (int j = 0; j < 8; ++j) {
      const bhalf8 v = *(const bhalf8*)(src + j * 8);
      *(bhalf8*)(dstbase + ((kq * 2 + j * 16) ^ ((col & 7) << 4))) = v;
    }
  }

  f32x4 acc[4];
  #pragma unroll
  for (int ct = 0; ct < 4; ++ct) {
    const float bc = bias[ct * 16 + lr];
    acc[ct][0] = bc; acc[ct][1] = bc; acc[ct][2] = bc; acc[ct][3] = bc;
  }

  __syncthreads();   // W staged

  const int ksw = (lr & 7) << 4;
  gemm_step<0>(ra, Wlds, lg, lr, ksw, acc);
  gemm_step<1>(ra, Wlds, lg, lr, ksw, acc);
  gemm_step<2>(ra, Wlds, lg, lr, ksw, acc);
  gemm_step<3>(ra, Wlds, lg, lr, ksw, acc);
  gemm_step<4>(ra, Wlds, lg, lr, ksw, acc);
  gemm_step<5>(ra, Wlds, lg, lr, ksw, acc);
  gemm_step<6>(ra, Wlds, lg, lr, ksw, acc);
  gemm_step<7>(ra, Wlds, lg, lr, ksw, acc);

  // ---- epilogue: emb16 writes + fused s1/s2 (row dots with a1,a2) ----
  float a1c[4], a2c[4];
  #pragma unroll
  for (int ct = 0; ct < 4; ++ct) {
    a1c[ct] = a[ct * 16 + lr];
    a2c[ct] = a[OUT_DIM + ct * 16 + lr];
  }
  #pragma unroll
  for (int i = 0; i < 4; ++i) {
    const int row = row0 + lg * 4 + i;   // C layout: col=lane&15, row=(lane>>4)*4+reg
    float p1 = 0.f, p2 = 0.f;
    #pragma unroll
    for (int ct = 0; ct < 4; ++ct) {
      const float e = acc[ct][i];
      p1 += e * a1c[ct];
      p2 += e * a2c[ct];
      if (row < N_NODES) emb16[(size_t)row * OUT_DIM + ct * 16 + lr] = f2bf(e);
    }
    #pragma unroll
    for (int o = 1; o < 16; o <<= 1) {
      p1 += __shfl_xor(p1, o, 64);
      p2 += __shfl_xor(p2, o, 64);
    }
    if (lr == 0 && row < N_NODES) { s1[row] = p1; s2[row] = p2; }
  }
}

// ---------------- K1c: bucket histogram (grid-stride, LDS-staged) ----------------
__global__ __launch_bounds__(256) void hist_kernel(const int* __restrict__ edges,
                                                   const int* __restrict__ flag,
                                                   int* __restrict__ bcnt) {
  __shared__ int lh[NBKT];
  const int t = threadIdx.x;
  for (int j = t; j < NBKT; j += 256) lh[j] = 0;
  __syncthreads();
  const int is64 = *flag;
  for (int e = blockIdx.x * 256 + t; e < E_EDGES; e += HIST_GRID * 256) {
    const int s = is64 ? ((const int4*)edges)[e].x : ((const int2*)edges)[e].x;
    atomicAdd(&lh[s >> BKT_SHIFT], 1);
  }
  __syncthreads();
  for (int j = t; j < NBKT; j += 256)
    if (lh[j]) atomicAdd(&bcnt[j], lh[j]);
}

// ---------------- K2: exclusive scan of bucket counts (single block) ----------------
__global__ __launch_bounds__(1024) void bucket_scan_kernel(const int* __restrict__ bcnt,
                                                           int* __restrict__ bbase,
                                                           int* __restrict__ bcur) {
  __shared__ int buf[1024];
  const int t = threadIdx.x;
  const int v = (t < NBKT) ? bcnt[t] : 0;
  buf[t] = v;
  __syncthreads();
  for (int o = 1; o < 1024; o <<= 1) {
    int add = (t >= o) ? buf[t - o] : 0;
    __syncthreads();
    buf[t] += add;
    __syncthreads();
  }
  if (t < NBKT) {
    const int ex = buf[t] - v;
    bbase[t] = ex;
    bcur[t]  = ex;
  }
  if (t == 0) bbase[NBKT] = E_EDGES;
}

// ---------------- K3: bucket scatter (single pass, edges cached in VGPRs) ----------------
__global__ __launch_bounds__(SC_BLOCK) void bucket_scatter_kernel(
    const int* __restrict__ edges, int* __restrict__ bcur,
    int2* __restrict__ pairs, const int* __restrict__ flag)
{
  __shared__ int lh[NBKT];
  __shared__ int lbase[NBKT];
  const int t = threadIdx.x;
  for (int j = t; j < NBKT; j += SC_BLOCK) lh[j] = 0;
  __syncthreads();

  const int is64 = *flag;
  const int e0 = blockIdx.x * SC_EDGES;
  int ss[SC_EPT], dd[SC_EPT];
  #pragma unroll
  for (int i = 0; i < SC_EPT; ++i) {
    const int e = e0 + t + i * SC_BLOCK;
    int s = -1, d = 0;
    if (e < E_EDGES) {
      if (is64) { int4 v = ((const int4*)edges)[e]; s = v.x; d = v.z; }
      else      { int2 v = ((const int2*)edges)[e]; s = v.x; d = v.y; }
      atomicAdd(&lh[s >> BKT_SHIFT], 1);
    }
    ss[i] = s; dd[i] = d;
  }
  __syncthreads();
  for (int j = t; j < NBKT; j += SC_BLOCK) {
    const int c = lh[j];
    lbase[j] = c ? atomicAdd(&bcur[j], c) : 0;
  }
  __syncthreads();
  for (int j = t; j < NBKT; j += SC_BLOCK) lh[j] = 0;
  __syncthreads();
  #pragma unroll
  for (int i = 0; i < SC_EPT; ++i) {
    const int s = ss[i];
    if (s >= 0) {
      const int b = s >> BKT_SHIFT;
      const int pos = lbase[b] + atomicAdd(&lh[b], 1);
      pairs[pos] = make_int2(s, dd[i]);
    }
  }
}

// ---------------- K4: fused per-bucket sort + weight + aggregation ----------------
// One block per bucket. Sort (dst,w) into LDS, then wave wv aggregates nodes
// [wv*32, wv*32+32), pairwise-interleaved (r, r+16) for 16 gathers in flight.
struct G8 {                 // one 8-edge gather batch (raw ushort rows + weights)
  unsigned u0,u1,u2,u3,u4,u5,u6,u7;
  float    w0,w1,w2,w3,w4,w5,w6,w7;
};

__device__ __forceinline__ G8 g8_issue(const unsigned short* __restrict__ emb16,
                                       const int2* __restrict__ lq,
                                       int seg, int j, int len, int lane) {
  const int4 A = *(const int4*)&lq[seg + j];
  const int4 B = *(const int4*)&lq[seg + j + 2];
  const int4 C = *(const int4*)&lq[seg + j + 4];
  const int4 D = *(const int4*)&lq[seg + j + 6];
  G8 g;
  const int d0 = (j + 0 < len) ? A.x : 0;  g.w0 = (j + 0 < len) ? __int_as_float(A.y) : 0.f;
  const int d1 = (j + 1 < len) ? A.z : 0;  g.w1 = (j + 1 < len) ? __int_as_float(A.w) : 0.f;
  const int d2 = (j + 2 < len) ? B.x : 0;  g.w2 = (j + 2 < len) ? __int_as_float(B.y) : 0.f;
  const int d3 = (j + 3 < len) ? B.z : 0;  g.w3 = (j + 3 < len) ? __int_as_float(B.w) : 0.f;
  const int d4 = (j + 4 < len) ? C.x : 0;  g.w4 = (j + 4 < len) ? __int_as_float(C.y) : 0.f;
  const int d5 = (j + 5 < len) ? C.z : 0;  g.w5 = (j + 5 < len) ? __int_as_float(C.w) : 0.f;
  const int d6 = (j + 6 < len) ? D.x : 0;  g.w6 = (j + 6 < len) ? __int_as_float(D.y) : 0.f;
  const int d7 = (j + 7 < len) ? D.z : 0;  g.w7 = (j + 7 < len) ? __int_as_float(D.w) : 0.f;
  g.u0 = emb16[(size_t)d0 * OUT_DIM + lane];
  g.u1 = emb16[(size_t)d1 * OUT_DIM + lane];
  g.u2 = emb16[(size_t)d2 * OUT_DIM + lane];
  g.u3 = emb16[(size_t)d3 * OUT_DIM + lane];
  g.u4 = emb16[(size_t)d4 * OUT_DIM + lane];
  g.u5 = emb16[(size_t)d5 * OUT_DIM + lane];
  g.u6 = emb16[(size_t)d6 * OUT_DIM + lane];
  g.u7 = emb16[(size_t)d7 * OUT_DIM + lane];
  return g;
}

__device__ __forceinline__ void g8_consume(const G8& g, float& acc, float& ws) {
  acc += g.w0 * bf2f((unsigned short)g.u0) + g.w1 * bf2f((unsigned short)g.u1)
       + g.w2 * bf2f((unsigned short)g.u2) + g.w3 * bf2f((unsigned short)g.u3)
       + g.w4 * bf2f((unsigned short)g.u4) + g.w5 * bf2f((unsigned short)g.u5)
       + g.w6 * bf2f((unsigned short)g.u6) + g.w7 * bf2f((unsigned short)g.u7);
  ws  += (g.w0 + g.w1 + g.w2 + g.w3) + (g.w4 + g.w5 + g.w6 + g.w7);
}

__global__ __launch_bounds__(256) void sortagg_kernel(
    const float* __restrict__ s1, const float* __restrict__ s2,
    const unsigned short* __restrict__ emb16,
    const int* __restrict__ bbase, const int2* __restrict__ pairs,
    float* __restrict__ out)
{
  __shared__ int2  lp[BUCKET_CAP];        // raw (src,dst)      20 KB
  __shared__ int2  lq[BUCKET_CAP + 8];    // sorted (dst,wbits) 20 KB
  __shared__ int   hist[BKT_NODES];
  __shared__ int   loff[BKT_NODES];
  __shared__ int   cur[BKT_NODES];
  __shared__ float ls1[BKT_NODES], ls2[BKT_NODES];

  const int b = blockIdx.x, t = threadIdx.x;
  const int nbase = b << BKT_SHIFT;
  const int nn = min(BKT_NODES, N_NODES - nbase);
  const int beg = bbase[b], end = bbase[b + 1];
  const int cnt = min(end - beg, BUCKET_CAP);

  if (t < BKT_NODES) {
    hist[t] = 0; cur[t] = 0;
    if (t < nn) { ls1[t] = s1[nbase + t]; ls2[t] = s2[nbase + t]; }
  }
  if (t < 8) lq[cnt + t] = make_int2(0, 0);   // zero pad after segment data
  __syncthreads();

  for (int j = t; j < cnt; j += 256) {
    const int2 p = pairs[beg + j];
    lp[j] = p;
    atomicAdd(&hist[p.x - nbase], 1);
  }
  __syncthreads();
  if (t < BKT_NODES) loff[t] = hist[t];
  __syncthreads();
  for (int o = 1; o < BKT_NODES; o <<= 1) {
    int add = 0;
    if (t < BKT_NODES && t >= o) add = loff[t - o];
    __syncthreads();
    if (t < BKT_NODES) loff[t] += add;
    __syncthreads();
  }
  if (t < BKT_NODES) loff[t] -= hist[t];     // exclusive
  __syncthreads();
  for (int j = t; j < cnt; j += 256) {
    const int2 p = lp[j];
    const int li = p.x - nbase;
    const int pos = loff[li] + atomicAdd(&cur[li], 1);
    const float lg = ls1[li] + s2[p.y];
    const float w = __expf(lg >= 0.f ? lg : SLOPE * lg);
    lq[pos] = make_int2(p.y, __float_as_int(w));
  }
  __syncthreads();

  // ---- aggregation: wave wv -> nodes wv*32 .. wv*32+31, interleaved (r, r+16) ----
  const int lane = t & 63;
  const int wv = t >> 6;
  for (int r = 0; r < 16; ++r) {
    const int liA = wv * 32 + r;
    const int liB = liA + 16;
    const bool vA = liA < nn, vB = liB < nn;       // wave-uniform
    int segA = 0, lenA = 0, segB = 0, lenB = 0;
    float accA = 0.f, wsA = 0.f, accB = 0.f, wsB = 0.f;
    if (vA) {
      segA = loff[liA]; lenA = hist[liA];
      const float es = bf2f(emb16[(size_t)(nbase + liA) * OUT_DIM + lane]);
      const float lg = ls1[liA] + ls2[liA];
      const float w = __expf(lg >= 0.f ? lg : SLOPE * lg);
      accA = w * es; wsA = w;
    }
    if (vB) {
      segB = loff[liB]; lenB = hist[liB];
      const float es = bf2f(emb16[(size_t)(nbase + liB) * OUT_DIM + lane]);
      const float lg = ls1[liB] + ls2[liB];
      const float w = __expf(lg >= 0.f ? lg : SLOPE * lg);
      accB = w * es; wsB = w;
    }
    int jA = 0, jB = 0;
    while ((jA < lenA) | (jB < lenB)) {
      G8 gA, gB;
      const bool doA = jA < lenA, doB = jB < lenB;
      if (doA) gA = g8_issue(emb16, lq, segA, jA, lenA, lane);
      if (doB) gB = g8_issue(emb16, lq, segB, jB, lenB, lane);
      if (doA) { g8_consume(gA, accA, wsA); jA += 8; }
      if (doB) { g8_consume(gB, accB, wsB); jB += 8; }
    }
    if (vA) out[(size_t)(nbase + liA) * OUT_DIM + lane] = accA / wsA;
    if (vB) out[(size_t)(nbase + liB) * OUT_DIM + lane] = accB / wsB;
  }
}

extern "C" void kernel_launch(void* const* d_in, const int* in_sizes, int n_in,
                              void* d_out, int out_size, void* d_ws, size_t ws_size,
                              hipStream_t stream) {
  const float* features = (const float*)d_in[0];
  const float* W        = (const float*)d_in[1];
  const float* b        = (const float*)d_in[2];
  const float* a        = (const float*)d_in[3];
  const int*   edges    = (const int*)d_in[4];
  float* out = (float*)d_out;

  // workspace layout (4B units)
  unsigned short* emb16 = (unsigned short*)d_ws;       // N*64 ushort = N*32 ints
  float* s1    = (float*)d_ws + (size_t)N_NODES * 32;  // N
  float* s2    = s1 + N_NODES;                         // N
  int*   bcnt  = (int*)(s2 + N_NODES);                 // NBKT
  int*   bbase = bcnt + NBKT;                          // NBKT+1
  int*   bcur  = bbase + NBKT + 1;                     // NBKT
  int*   flag  = bcur + NBKT;                          // 1 (+pad)
  int2*  pairs = (int2*)(flag + 8);                    // E (8B each)
  short* W16   = (short*)(pairs + E_EDGES);            // 16384 shorts (32 KB)

  hipLaunchKernelGGL(zero_detect_kernel, dim3(8), dim3(256), 0, stream,
                     bcnt, edges, flag, W, W16);
  hipLaunchKernelGGL(embed_kernel, dim3(EMB_BLOCKS), dim3(256), 0, stream,
                     features, W16, b, a, emb16, s1, s2);
  hipLaunchKernelGGL(hist_kernel, dim3(HIST_GRID), dim3(256), 0, stream,
                     edges, flag, bcnt);
  hipLaunchKernelGGL(bucket_scan_kernel, dim3(1), dim3(1024), 0, stream,
                     bcnt, bbase, bcur);
  hipLaunchKernelGGL(bucket_scatter_kernel, dim3(SC_GRID), dim3(SC_BLOCK), 0, stream,
                     edges, bcur, pairs, flag);
  hipLaunchKernelGGL(sortagg_kernel, dim3(NBKT), dim3(256), 0, stream,
                     s1, s2, emb16, bbase, pairs, out);
}

// Round 10
// 152.762 us; speedup vs baseline: 1.4306x; 1.4306x over previous
//
#include <hip/hip_runtime.h>

#define N_NODES 100000
#define E_EDGES 1600000
#define IN_DIM  256
#define OUT_DIM 64
#define SLOPE   0.1f

#define BKT_SHIFT  7
#define BKT_NODES  128
#define NBKT       ((N_NODES + BKT_NODES - 1) / BKT_NODES)   // 782
#define BUCKET_CAP 3072
#define SC_BLOCK   1024
#define SC_EPT     16
#define SC_EDGES   (SC_BLOCK * SC_EPT)                        // 16384
#define SC_GRID    ((E_EDGES + SC_EDGES - 1) / SC_EDGES)      // 98
#define EMB_BLOCKS ((N_NODES + 63) / 64)                      // 1563

typedef __attribute__((ext_vector_type(8))) short bhalf8;
typedef __attribute__((ext_vector_type(4))) float f32x4;
typedef __attribute__((ext_vector_type(4))) unsigned u32x4;

__device__ __forceinline__ unsigned short f2bf(float x) {
  unsigned u = __float_as_uint(x);
  u = (u + 0x7fffu + ((u >> 16) & 1u)) >> 16;   // RNE
  return (unsigned short)u;
}
__device__ __forceinline__ float bf2f(unsigned short u) {
  return __uint_as_float((unsigned)u << 16);
}
__device__ __forceinline__ unsigned cvtpk(float lo, float hi) {   // RNE pack, 1 inst
  unsigned r;
  asm("v_cvt_pk_bf16_f32 %0, %1, %2" : "=v"(r) : "v"(lo), "v"(hi));
  return r;
}

// -------- K0: zero bucket counters + detect edge layout + W -> bf16 --------
__global__ __launch_bounds__(256) void zero_detect_kernel(
    int* __restrict__ bcnt, const int* __restrict__ edges, int* __restrict__ flag,
    const float* __restrict__ W, short* __restrict__ W16) {
  const int i = blockIdx.x * blockDim.x + threadIdx.x;   // 8 blocks x 256 = 2048
  if (i < NBKT) bcnt[i] = 0;
  if (i == 0) {
    int all0 = 1;
    for (int j = 0; j < 64; ++j)
      if (edges[2 * j + 1] != 0) all0 = 0;
    *flag = all0;  // 1 => int64 layout (high dwords zero), 0 => int32
  }
  {
    const int base = i * 8;
    const float4 f0 = *(const float4*)&W[base];
    const float4 f1 = *(const float4*)&W[base + 4];
    bhalf8 v;
    v[0] = f2bf(f0.x); v[1] = f2bf(f0.y); v[2] = f2bf(f0.z); v[3] = f2bf(f0.w);
    v[4] = f2bf(f1.x); v[5] = f2bf(f1.y); v[6] = f2bf(f1.z); v[7] = f2bf(f1.w);
    *(bhalf8*)&W16[base] = v;
  }
}

// ---------------- K1: emb16 = bf16(X@W^T + b); full-row A upfront; fused hist ----------
template<int KS>
__device__ __forceinline__ void gemm_step(const float4 (&ra)[8][2],
                                          const short* __restrict__ Wlds,
                                          int lg, int lr, int ksw, f32x4 (&acc)[4]) {
  union { u32x4 u; bhalf8 h; } cv;
  cv.u[0] = cvtpk(ra[KS][0].x, ra[KS][0].y);
  cv.u[1] = cvtpk(ra[KS][0].z, ra[KS][0].w);
  cv.u[2] = cvtpk(ra[KS][1].x, ra[KS][1].y);
  cv.u[3] = cvtpk(ra[KS][1].z, ra[KS][1].w);
  bhalf8 bf[4];
  #pragma unroll
  for (int ct = 0; ct < 4; ++ct) {
    const int col_l = ct * 16 + lr;
    bf[ct] = *(const bhalf8*)((const char*)Wlds + col_l * 512 + ((lg * 16 + KS * 64) ^ ksw));
  }
  #pragma unroll
  for (int ct = 0; ct < 4; ++ct)
    acc[ct] = __builtin_amdgcn_mfma_f32_16x16x32_bf16(cv.h, bf[ct], acc[ct], 0, 0, 0);
}

__global__ __launch_bounds__(256) void embed_kernel(
    const float* __restrict__ features, const short* __restrict__ W16,
    const float* __restrict__ bias, const float* __restrict__ a,
    unsigned short* __restrict__ emb16, float* __restrict__ s1, float* __restrict__ s2,
    const int* __restrict__ edges, const int* __restrict__ flag, int* __restrict__ bcnt)
{
  __shared__ short Wlds[64 * 256];    // 32 KB, col stride 512 B, byte^((col&7)<<4)
  __shared__ int   lh[NBKT];          // 3.1 KB bucket histogram

  const int t = threadIdx.x;
  const int w = t >> 6;
  const int l = t & 63;
  const int lg = l >> 4;      // 0..3  (k-chunk group)
  const int lr = l & 15;      // 0..15 (row/col within tile)
  const int row0 = blockIdx.x * 64 + w * 16;   // this wave's 16 rows

  const int rowc = min(row0 + lr, N_NODES - 1);
  const float* arow = &features[(size_t)rowc * IN_DIM + lg * 8];

  // ---- issue ALL A loads up front (16 dwordx4 per lane, 256 B in flight) ----
  float4 ra[8][2];
  #pragma unroll
  for (int ks = 0; ks < 8; ++ks) {
    ra[ks][0] = *(const float4*)(arow + ks * 32);
    ra[ks][1] = *(const float4*)(arow + ks * 32 + 4);
  }

  // ---- stage W16 -> LDS (pure bf16 copy, swizzled), overlaps A latency ----
  {
    const int col = t >> 2;
    const int kq  = (t & 3) * 64;            // start k (elements)
    const short* src = W16 + col * IN_DIM + kq;
    char* dstbase = (char*)Wlds + col * 512;
    #pragma unroll
    for (int j = 0; j < 8; ++j) {
      const bhalf8 v = *(const bhalf8*)(src + j * 8);
      *(bhalf8*)(dstbase + ((kq * 2 + j * 16) ^ ((col & 7) << 4))) = v;
    }
  }

  f32x4 acc[4];
  #pragma unroll
  for (int ct = 0; ct < 4; ++ct) {
    const float bc = bias[ct * 16 + lr];
    acc[ct][0] = bc; acc[ct][1] = bc; acc[ct][2] = bc; acc[ct][3] = bc;
  }

  __syncthreads();   // W staged

  const int ksw = (lr & 7) << 4;
  gemm_step<0>(ra, Wlds, lg, lr, ksw, acc);
  gemm_step<1>(ra, Wlds, lg, lr, ksw, acc);
  gemm_step<2>(ra, Wlds, lg, lr, ksw, acc);
  gemm_step<3>(ra, Wlds, lg, lr, ksw, acc);
  gemm_step<4>(ra, Wlds, lg, lr, ksw, acc);
  gemm_step<5>(ra, Wlds, lg, lr, ksw, acc);
  gemm_step<6>(ra, Wlds, lg, lr, ksw, acc);
  gemm_step<7>(ra, Wlds, lg, lr, ksw, acc);

  // zero hist while epilogue runs (Wlds no longer read; lh is separate)
  for (int j = t; j < NBKT; j += 256) lh[j] = 0;

  // ---- epilogue: emb16 writes + fused s1/s2 (row dots with a1,a2) ----
  float a1c[4], a2c[4];
  #pragma unroll
  for (int ct = 0; ct < 4; ++ct) {
    a1c[ct] = a[ct * 16 + lr];
    a2c[ct] = a[OUT_DIM + ct * 16 + lr];
  }
  #pragma unroll
  for (int i = 0; i < 4; ++i) {
    const int row = row0 + lg * 4 + i;   // C layout: col=lane&15, row=(lane>>4)*4+reg
    float p1 = 0.f, p2 = 0.f;
    #pragma unroll
    for (int ct = 0; ct < 4; ++ct) {
      const float e = acc[ct][i];
      p1 += e * a1c[ct];
      p2 += e * a2c[ct];
      if (row < N_NODES) emb16[(size_t)row * OUT_DIM + ct * 16 + lr] = f2bf(e);
    }
    #pragma unroll
    for (int o = 1; o < 16; o <<= 1) {
      p1 += __shfl_xor(p1, o, 64);
      p2 += __shfl_xor(p2, o, 64);
    }
    if (lr == 0 && row < N_NODES) { s1[row] = p1; s2[row] = p2; }
  }

  // ---- fused bucket histogram over this block's 1024-edge chunk ----
  __syncthreads();
  const int is64 = *flag;
  const int e0 = blockIdx.x * 1024;
  #pragma unroll
  for (int i = 0; i < 4; ++i) {
    const int e = e0 + t + i * 256;
    if (e < E_EDGES) {
      const int s = is64 ? ((const int4*)edges)[e].x : ((const int2*)edges)[e].x;
      atomicAdd(&lh[s >> BKT_SHIFT], 1);
    }
  }
  __syncthreads();
  for (int j = t; j < NBKT; j += 256)
    if (lh[j]) atomicAdd(&bcnt[j], lh[j]);
}

// ---------------- K2: exclusive scan of bucket counts (single block) ----------------
__global__ __launch_bounds__(1024) void bucket_scan_kernel(const int* __restrict__ bcnt,
                                                           int* __restrict__ bbase,
                                                           int* __restrict__ bcur) {
  __shared__ int buf[1024];
  const int t = threadIdx.x;
  const int v = (t < NBKT) ? bcnt[t] : 0;
  buf[t] = v;
  __syncthreads();
  for (int o = 1; o < 1024; o <<= 1) {
    int add = (t >= o) ? buf[t - o] : 0;
    __syncthreads();
    buf[t] += add;
    __syncthreads();
  }
  if (t < NBKT) {
    const int ex = buf[t] - v;
    bbase[t] = ex;
    bcur[t]  = ex;
  }
  if (t == 0) bbase[NBKT] = E_EDGES;
}

// ---------------- K3: bucket scatter (single pass, edges cached in VGPRs) ----------------
__global__ __launch_bounds__(SC_BLOCK) void bucket_scatter_kernel(
    const int* __restrict__ edges, int* __restrict__ bcur,
    int2* __restrict__ pairs, const int* __restrict__ flag)
{
  __shared__ int lh[NBKT];
  __shared__ int lbase[NBKT];
  const int t = threadIdx.x;
  for (int j = t; j < NBKT; j += SC_BLOCK) lh[j] = 0;
  __syncthreads();

  const int is64 = *flag;
  const int e0 = blockIdx.x * SC_EDGES;
  int ss[SC_EPT], dd[SC_EPT];
  #pragma unroll
  for (int i = 0; i < SC_EPT; ++i) {
    const int e = e0 + t + i * SC_BLOCK;
    int s = -1, d = 0;
    if (e < E_EDGES) {
      if (is64) { int4 v = ((const int4*)edges)[e]; s = v.x; d = v.z; }
      else      { int2 v = ((const int2*)edges)[e]; s = v.x; d = v.y; }
      atomicAdd(&lh[s >> BKT_SHIFT], 1);
    }
    ss[i] = s; dd[i] = d;
  }
  __syncthreads();
  for (int j = t; j < NBKT; j += SC_BLOCK) {
    const int c = lh[j];
    lbase[j] = c ? atomicAdd(&bcur[j], c) : 0;
  }
  __syncthreads();
  for (int j = t; j < NBKT; j += SC_BLOCK) lh[j] = 0;
  __syncthreads();
  #pragma unroll
  for (int i = 0; i < SC_EPT; ++i) {
    const int s = ss[i];
    if (s >= 0) {
      const int b = s >> BKT_SHIFT;
      const int pos = lbase[b] + atomicAdd(&lh[b], 1);
      pairs[pos] = make_int2(s, dd[i]);
    }
  }
}

// ---------------- K4: per-bucket counting sort + weight precompute (in place) --------
__global__ __launch_bounds__(256) void bucket_sort_kernel(
    const float* __restrict__ s1, const float* __restrict__ s2,
    const int* __restrict__ bbase, int2* __restrict__ pairs, int* __restrict__ off)
{
  __shared__ int2  lp[BUCKET_CAP];
  __shared__ int   hist[BKT_NODES];
  __shared__ int   loff[BKT_NODES];
  __shared__ float ls1[BKT_NODES];
  const int b = blockIdx.x, t = threadIdx.x;
  const int nbase = b << BKT_SHIFT;
  const int nn = min(BKT_NODES, N_NODES - nbase);
  const int beg = bbase[b], end = bbase[b + 1];
  const int cnt = min(end - beg, BUCKET_CAP);

  if (t < BKT_NODES) {
    hist[t] = 0;
    if (t < nn) ls1[t] = s1[nbase + t];
  }
  __syncthreads();
  for (int j = t; j < cnt; j += 256) {
    const int2 p = pairs[beg + j];
    lp[j] = p;
    atomicAdd(&hist[p.x - nbase], 1);
  }
  __syncthreads();
  if (t < BKT_NODES) loff[t] = hist[t];
  __syncthreads();
  for (int o = 1; o < BKT_NODES; o <<= 1) {
    int add = 0;
    if (t < BKT_NODES && t >= o) add = loff[t - o];
    __syncthreads();
    if (t < BKT_NODES) loff[t] += add;
    __syncthreads();
  }
  int excl = 0;
  if (t < BKT_NODES) {
    excl = loff[t] - hist[t];
    if (t < nn) off[nbase + t] = beg + excl;
  }
  if (b == NBKT - 1 && t == 0) off[N_NODES] = E_EDGES;
  __syncthreads();
  if (t < BKT_NODES) { loff[t] = excl; hist[t] = 0; }
  __syncthreads();
  for (int j = t; j < cnt; j += 256) {
    const int2 p = lp[j];
    const int li = p.x - nbase;
    const int pos = beg + loff[li] + atomicAdd(&hist[li], 1);
    const float lg = ls1[li] + s2[p.y];
    const float w = __expf(lg >= 0.f ? lg : SLOPE * lg);
    pairs[pos] = make_int2(p.y, __float_as_int(w));
  }
}

// ---------------- K5: one wave per node; 2x G8 gather batches in flight ----------------
struct G8 {
  unsigned u0,u1,u2,u3,u4,u5,u6,u7;
  float    w0,w1,w2,w3,w4,w5,w6,w7;
};

__device__ __forceinline__ G8 g8_issue(const unsigned short* __restrict__ emb16,
                                       const int2* __restrict__ lq, int q, int lane) {
  const int4 A = *(const int4*)&lq[q];
  const int4 B = *(const int4*)&lq[q + 2];
  const int4 C = *(const int4*)&lq[q + 4];
  const int4 D = *(const int4*)&lq[q + 6];
  G8 g;
  g.w0 = __int_as_float(A.y); g.w1 = __int_as_float(A.w);
  g.w2 = __int_as_float(B.y); g.w3 = __int_as_float(B.w);
  g.w4 = __int_as_float(C.y); g.w5 = __int_as_float(C.w);
  g.w6 = __int_as_float(D.y); g.w7 = __int_as_float(D.w);
  g.u0 = emb16[(size_t)A.x * OUT_DIM + lane];
  g.u1 = emb16[(size_t)A.z * OUT_DIM + lane];
  g.u2 = emb16[(size_t)B.x * OUT_DIM + lane];
  g.u3 = emb16[(size_t)B.z * OUT_DIM + lane];
  g.u4 = emb16[(size_t)C.x * OUT_DIM + lane];
  g.u5 = emb16[(size_t)C.z * OUT_DIM + lane];
  g.u6 = emb16[(size_t)D.x * OUT_DIM + lane];
  g.u7 = emb16[(size_t)D.z * OUT_DIM + lane];
  return g;
}

__device__ __forceinline__ void g8_consume(const G8& g, float& acc, float& ws) {
  acc += g.w0 * bf2f((unsigned short)g.u0) + g.w1 * bf2f((unsigned short)g.u1)
       + g.w2 * bf2f((unsigned short)g.u2) + g.w3 * bf2f((unsigned short)g.u3)
       + g.w4 * bf2f((unsigned short)g.u4) + g.w5 * bf2f((unsigned short)g.u5)
       + g.w6 * bf2f((unsigned short)g.u6) + g.w7 * bf2f((unsigned short)g.u7);
  ws  += (g.w0 + g.w1 + g.w2 + g.w3) + (g.w4 + g.w5 + g.w6 + g.w7);
}

__global__ __launch_bounds__(256) void aggregate_kernel(
    const unsigned short* __restrict__ emb16,
    const float* __restrict__ s1, const float* __restrict__ s2,
    const int* __restrict__ off, const int2* __restrict__ pairs, float* __restrict__ out)
{
  __shared__ int2 buf[4][64];
  const int lane = threadIdx.x & 63;
  const int wv   = threadIdx.x >> 6;
  const int node = blockIdx.x * 4 + wv;
  if (node >= N_NODES) return;

  const float esel = bf2f(emb16[(size_t)node * OUT_DIM + lane]);
  const float lgs = s1[node] + s2[node];
  const float wself = __expf(lgs >= 0.f ? lgs : SLOPE * lgs);
  float accA = wself * esel, accB = 0.f;
  float wsA = wself, wsB = 0.f;

  const int beg = off[node], end = off[node + 1];
  for (int j0 = beg; j0 < end; j0 += 64) {
    const int idx = j0 + lane;
    buf[wv][lane] = (idx < end) ? pairs[idx] : make_int2(0, 0);  // w=0 pads
    const int m = min(64, end - j0);
    for (int q = 0; q < m; q += 16) {          // padded entries are (d=0, w=0): guard-free
      const G8 gA = g8_issue(emb16, buf[wv], q, lane);
      const G8 gB = g8_issue(emb16, buf[wv], q + 8, lane);
      g8_consume(gA, accA, wsA);
      g8_consume(gB, accB, wsB);
    }
  }
  out[(size_t)node * OUT_DIM + lane] = (accA + accB) / (wsA + wsB);
}

extern "C" void kernel_launch(void* const* d_in, const int* in_sizes, int n_in,
                              void* d_out, int out_size, void* d_ws, size_t ws_size,
                              hipStream_t stream) {
  const float* features = (const float*)d_in[0];
  const float* W        = (const float*)d_in[1];
  const float* b        = (const float*)d_in[2];
  const float* a        = (const float*)d_in[3];
  const int*   edges    = (const int*)d_in[4];
  float* out = (float*)d_out;

  // workspace layout (4B units)
  unsigned short* emb16 = (unsigned short*)d_ws;       // N*64 ushort = N*32 ints
  float* s1    = (float*)d_ws + (size_t)N_NODES * 32;  // N
  float* s2    = s1 + N_NODES;                         // N
  int*   off   = (int*)(s2 + N_NODES);                 // N+1
  int*   bcnt  = off + N_NODES + 1;                    // NBKT
  int*   bbase = bcnt + NBKT;                          // NBKT+1
  int*   bcur  = bbase + NBKT + 1;                     // NBKT
  int*   flag  = bcur + NBKT;                          // 1 (+pad)
  int2*  pairs = (int2*)(flag + 8);                    // E (8B each)
  short* W16   = (short*)(pairs + E_EDGES);            // 16384 shorts (32 KB)

  hipLaunchKernelGGL(zero_detect_kernel, dim3(8), dim3(256), 0, stream,
                     bcnt, edges, flag, W, W16);
  hipLaunchKernelGGL(embed_kernel, dim3(EMB_BLOCKS), dim3(256), 0, stream,
                     features, W16, b, a, emb16, s1, s2, edges, flag, bcnt);
  hipLaunchKernelGGL(bucket_scan_kernel, dim3(1), dim3(1024), 0, stream,
                     bcnt, bbase, bcur);
  hipLaunchKernelGGL(bucket_scatter_kernel, dim3(SC_GRID), dim3(SC_BLOCK), 0, stream,
                     edges, bcur, pairs, flag);
  hipLaunchKernelGGL(bucket_sort_kernel, dim3(NBKT), dim3(256), 0, stream,
                     s1, s2, bbase, pairs, off);
  hipLaunchKernelGGL(aggregate_kernel, dim3((N_NODES + 3) / 4), dim3(256), 0, stream,
                     emb16, s1, s2, off, pairs, out);
}